// Round 12
// baseline (161.442 us; speedup 1.0000x reference)
//
#include <hip/hip_runtime.h>
#include <math.h>

#define DIMX 128
#define HIDX 256
#define NBX 2048
#define NTOTX 32768
#define NMAXX 32
#define VMID 192
#define SMID 128
#define DMID 192

#define EROWS 64
#define SP 68         // [k][row] pitch, %4==0 -> 16B-aligned b128 reads at r0 multiples of 4
#define NSEGMAX 128   // segment-size cap (multinomial mean 16, P(n>60) ~ 1e-16)

__device__ __forceinline__ float mishf(float v) {
    // exact identity: tanh(log1p(e^v)) = (u^2+2u)/(u^2+2u+2), u=e^v
    if (v > 20.0f) return v;          // tanh(softplus(v)) == 1.0f in fp32
    float u = expf(v);
    float t = u * (u + 2.0f);
    return v * (t / (t + 2.0f));
}

// weight repack, j-major for lane-coalesced f4 loads:
// wI1[((kg*6 + j)*32 + cg)*4 + kk] = w1[4kg+kk][cg*6 + j]   (kg<32, j<6, cg<32)
// wI2[((kg*8 + j)*32 + cg)*4 + kk] = w2[4kg+kk][cg*8 + j]   (kg<48, j<8, cg<32)
__global__ void k_wt(const float* __restrict__ w1, const float* __restrict__ w2,
                     float* __restrict__ wI1, float* __restrict__ wI2) {
    int i = blockIdx.x * blockDim.x + threadIdx.x;
    if (i < DIMX * VMID) {
        int k = i / VMID, c = i % VMID;
        int kg = k >> 2, kk = k & 3, cg = c / 6, j = c % 6;
        wI1[(((kg * 6 + j) * 32) + cg) * 4 + kk] = w1[i];
    }
    int i2 = i - DIMX * VMID;
    if (i2 >= 0 && i2 < VMID * HIDX) {
        int k = i2 / HIDX, c = i2 % HIDX;
        int kg = k >> 2, kk = k & 3, cg = c >> 3, j = c & 7;
        wI2[(((kg * 8 + j) * 32) + cg) * 4 + kk] = w2[i2];
    }
}

// fused encoder + mag. 256 thr = 8 rowgroups x 32 colgroups; 8 rows x 6/8 cols
// per thread. Weights: j-major repacked f4 (coalesced, 4 k per load). x/act via
// LDS b128 broadcast. LN fully in-register (half-wave shfl).
__global__ __launch_bounds__(256, 2) void k_enc(const float* __restrict__ x,
    const float* __restrict__ rw, const float* __restrict__ rb,
    const float4* __restrict__ wI1, const float* __restrict__ b1,
    const float* __restrict__ g1, const float* __restrict__ be1,
    const float4* __restrict__ wI2, const float* __restrict__ b2,
    float* __restrict__ h, float* __restrict__ mag) {
    __shared__ __align__(16) float sT[VMID * SP];  // xT[128][SP] then actT[192][SP]
    int tid = threadIdx.x;
    int rowbase = blockIdx.x * EROWS;

    // stage x^T: coalesced float4 reads
#pragma unroll
    for (int it = 0; it < 8; it++) {
        int idx = it * 256 + tid;
        int r = idx >> 5, kq = idx & 31;
        float4 v = ((const float4*)x)[(size_t)(rowbase + r) * 32 + kq];
        sT[(4 * kq + 0) * SP + r] = v.x;
        sT[(4 * kq + 1) * SP + r] = v.y;
        sT[(4 * kq + 2) * SP + r] = v.z;
        sT[(4 * kq + 3) * SP + r] = v.w;
    }
    __syncthreads();

    // mag = x . rank_w (wave 0; xT read-only here)
    if (tid < EROWS) {
        float s = 0.0f;
        for (int k = 0; k < DIMX; k++) s += sT[k * SP + tid] * rw[k];
        mag[rowbase + tid] = s + rb[0];
    }

    int cg = tid & 31;       // colgroup (lane within half-wave)
    int rg = tid >> 5;       // rowgroup 0..7
    int r0 = rg * 8;

    // ---- GEMM1: 8 rows x 6 cols/thread; per kg: 6 coalesced f4 + 8 b128 + 192 FMA ----
    float acc[6][8];
#pragma unroll
    for (int j = 0; j < 6; j++)
#pragma unroll
        for (int i = 0; i < 8; i++) acc[j][i] = 0.0f;
    const float4* w1p = wI1 + cg;
#pragma unroll 2
    for (int kg = 0; kg < DIMX / 4; kg++) {
        float4 wv[6];
#pragma unroll
        for (int j = 0; j < 6; j++) wv[j] = w1p[(kg * 6 + j) * 32];
#pragma unroll
        for (int kk = 0; kk < 4; kk++) {
            const float4* xp = (const float4*)&sT[(4 * kg + kk) * SP + r0];
            float4 t0 = xp[0], t1 = xp[1];
            float xv[8] = {t0.x, t0.y, t0.z, t0.w, t1.x, t1.y, t1.z, t1.w};
#pragma unroll
            for (int j = 0; j < 6; j++) {
                float w = ((const float*)&wv[j])[kk];   // kk is unroll-static
#pragma unroll
                for (int i = 0; i < 8; i++) acc[j][i] += w * xv[i];
            }
        }
    }

    // ---- LayerNorm + mish in registers; row's 192 cols live in one half-wave ----
    float b1v[6], g1v[6], e1v[6];
#pragma unroll
    for (int j = 0; j < 6; j++) {
        b1v[j] = b1[cg * 6 + j];
        g1v[j] = g1[cg * 6 + j];
        e1v[j] = be1[cg * 6 + j];
    }
#pragma unroll
    for (int i = 0; i < 8; i++) {
        float s = 0.0f;
#pragma unroll
        for (int j = 0; j < 6; j++) { acc[j][i] += b1v[j]; s += acc[j][i]; }
#pragma unroll
        for (int off = 16; off; off >>= 1) s += __shfl_xor(s, off, 64);
        float mean = s * (1.0f / 192.0f);
        float q = 0.0f;
#pragma unroll
        for (int j = 0; j < 6; j++) {
            acc[j][i] -= mean;
            q += acc[j][i] * acc[j][i];
        }
#pragma unroll
        for (int off = 16; off; off >>= 1) q += __shfl_xor(q, off, 64);
        float inv = 1.0f / sqrtf(q * (1.0f / 192.0f) + 1e-5f);
#pragma unroll
        for (int j = 0; j < 6; j++)
            acc[j][i] = mishf(acc[j][i] * inv * g1v[j] + e1v[j]);
    }
    __syncthreads();   // all GEMM1 LDS reads done before overwrite
#pragma unroll
    for (int j = 0; j < 6; j++)
#pragma unroll
        for (int i = 0; i < 8; i++)
            sT[(cg * 6 + j) * SP + r0 + i] = acc[j][i];
    __syncthreads();

    // ---- GEMM2: 8 rows x 8 cols/thread; per kg: 8 coalesced f4 + 8 b128 + 256 FMA ----
    float c2[8][8];
#pragma unroll
    for (int j = 0; j < 8; j++)
#pragma unroll
        for (int i = 0; i < 8; i++) c2[j][i] = 0.0f;
    const float4* w2p = wI2 + cg;
#pragma unroll 2
    for (int kg = 0; kg < VMID / 4; kg++) {
        float4 wv[8];
#pragma unroll
        for (int j = 0; j < 8; j++) wv[j] = w2p[(kg * 8 + j) * 32];
#pragma unroll
        for (int kk = 0; kk < 4; kk++) {
            const float4* ap = (const float4*)&sT[(4 * kg + kk) * SP + r0];
            float4 t0 = ap[0], t1 = ap[1];
            float av[8] = {t0.x, t0.y, t0.z, t0.w, t1.x, t1.y, t1.z, t1.w};
#pragma unroll
            for (int j = 0; j < 8; j++) {
                float w = ((const float*)&wv[j])[kk];
#pragma unroll
                for (int i = 0; i < 8; i++) c2[j][i] += w * av[i];
            }
        }
    }
    float b2v[8];
#pragma unroll
    for (int j = 0; j < 8; j++) b2v[j] = b2[cg * 8 + j];
    // store h: thread's 8 cols are contiguous -> 2 f4 per row
#pragma unroll
    for (int i = 0; i < 8; i++) {
        float* hp = h + (size_t)(rowbase + r0 + i) * HIDX + cg * 8;
        float4 v0 = {c2[0][i] + b2v[0], c2[1][i] + b2v[1], c2[2][i] + b2v[2], c2[3][i] + b2v[3]};
        float4 v1 = {c2[4][i] + b2v[4], c2[5][i] + b2v[5], c2[6][i] + b2v[6], c2[7][i] + b2v[7]};
        ((float4*)hp)[0] = v0;
        ((float4*)hp)[1] = v1;
    }
}

// fused: seg-bounds + in-LDS rank + z (inline sincos) + size MLP + zc/mask/npred
__global__ __launch_bounds__(256) void k_z(const float* __restrict__ h,
    const int* __restrict__ batch, const float* __restrict__ mag,
    const float* __restrict__ cw, const float* __restrict__ cb,
    const float* __restrict__ sw1, const float* __restrict__ sb1,
    const float* __restrict__ sg, const float* __restrict__ sbe,
    const float* __restrict__ sw2, const float* __restrict__ sb2,
    float* __restrict__ zcre, float* __restrict__ zim,
    float* __restrict__ out_mask, float* __restrict__ out_np,
    int* __restrict__ npredi) {
    __shared__ float zrow[HIDX];
    __shared__ float magL[NSEGMAX];
    __shared__ int   ordL[NSEGMAX];
    __shared__ int   shs, shn;
    __shared__ float red0[2], red1[2], red2[2];
    int b = blockIdx.x, j = threadIdx.x;
    if (j == 0) {
        int lo = 0, hi = NTOTX;
        while (lo < hi) { int m = (lo + hi) >> 1; if (batch[m] < b) lo = m + 1; else hi = m; }
        int stt = lo;
        hi = NTOTX;
        while (lo < hi) { int m = (lo + hi) >> 1; if (batch[m] <= b) lo = m + 1; else hi = m; }
        shs = stt; shn = lo - stt;
    }
    __syncthreads();
    int s = shs, n_true = shn;
    int n = (n_true < NSEGMAX) ? n_true : NSEGMAX;
    if (j < n) magL[j] = mag[s + j];
    __syncthreads();
    if (j < n) {                          // stable rank within segment (lexsort tie: idx)
        float mi = magL[j];
        int rk = 0;
        for (int q = 0; q < n; q++) {
            float mq = magL[q];
            rk += (mq < mi) || (mq == mi && q < j);
        }
        ordL[rk] = s + j;
    }
    __syncthreads();

    float t = (float)j * (1.0f / 255.0f);
    float zr = 0.f, zi = 0.f;
    int p = 0;
    for (; p + 1 < n; p += 2) {           // accumulation ORDER = p ascending (fp32-exact)
        int e0 = ordL[p], e1 = ordL[p + 1];
        float hv0 = h[(size_t)e0 * HIDX + j];
        float hv1 = h[(size_t)e1 * HIDX + j];
        float sv0, cv0, sv1, cv1;
        sincosf((t * (float)p) * 8.0f, &sv0, &cv0);
        sincosf((t * (float)(p + 1)) * 8.0f, &sv1, &cv1);
        zr += hv0 * cv0; zi += hv0 * sv0;
        zr += hv1 * cv1; zi += hv1 * sv1;
    }
    if (p < n) {
        int e = ordL[p];
        float hv = h[(size_t)e * HIDX + j];
        float sv, cv;
        sincosf((t * (float)p) * 8.0f, &sv, &cv);
        zr += hv * cv; zi += hv * sv;
    }
    float nf = (float)n_true;
    float zrev = zr + nf * cw[j] + cb[j];
    zrow[j] = zrev;
    zim[(size_t)b * HIDX + j] = zi;
    __syncthreads();

    // size MLP (threads 0..127 active; all threads hit barriers)
    float v = 0.0f;
    if (j < SMID) {
        v = sb1[j];
        for (int k = 0; k < HIDX; k++) v += zrow[k] * sw1[k * SMID + j];
    }
    float sa = v;
#pragma unroll
    for (int off = 32; off; off >>= 1) sa += __shfl_xor(sa, off, 64);
    if (j < SMID && (j & 63) == 0) red0[j >> 6] = sa;
    __syncthreads();
    float mean = (red0[0] + red0[1]) / 128.0f;
    float d = v - mean;
    float q2 = d * d;
#pragma unroll
    for (int off = 32; off; off >>= 1) q2 += __shfl_xor(q2, off, 64);
    if (j < SMID && (j & 63) == 0) red1[j >> 6] = q2;
    __syncthreads();
    float var = (red1[0] + red1[1]) / 128.0f;
    float p2 = 0.0f;
    if (j < SMID) {
        float lv = d * (1.0f / sqrtf(var + 1e-5f)) * sg[j] + sbe[j];
        p2 = mishf(lv) * sw2[j];
    }
#pragma unroll
    for (int off = 32; off; off >>= 1) p2 += __shfl_xor(p2, off, 64);
    if (j < SMID && (j & 63) == 0) red2[j >> 6] = p2;
    __syncthreads();
    float h2 = red2[0] + red2[1] + sb2[0];
    float npf = fmaxf(rintf(h2), 0.0f);     // rintf == round-half-even == jnp.round
    int npi = min((int)npf, NMAXX);
    zcre[(size_t)b * HIDX + j] = zrow[j] - (npf * cw[j] + cb[j]);
    if (j < NMAXX) out_mask[b * NMAXX + j] = (j < npi) ? 1.0f : 0.0f;
    if (j == 0) { out_np[b] = (float)npi; npredi[b] = npi; }
}

// decoder: per-(m,b) blocks; masked rows write zeros; inline sincos keys
__global__ __launch_bounds__(256) void k_dec(const float* __restrict__ zcre,
    const float* __restrict__ zim, const int* __restrict__ npredi,
    const float* __restrict__ w1, const float* __restrict__ b1,
    const float* __restrict__ w2, const float* __restrict__ b2,
    float* __restrict__ xr) {
    int m = blockIdx.x, b = blockIdx.y;
    int tid = threadIdx.x;
    size_t row = (size_t)b * NMAXX + m;
    if (m >= npredi[b]) {
        if (tid < DIMX) xr[row * DIMX + tid] = 0.0f;
        return;
    }
    __shared__ float zp[HIDX];
    __shared__ float a[DMID];
    {
        float t = (float)tid * (1.0f / 255.0f);
        float sv, cv;
        sincosf((t * (float)m) * 8.0f, &sv, &cv);
        zp[tid] = zcre[(size_t)b * HIDX + tid] * cv - zim[(size_t)b * HIDX + tid] * sv;
    }
    __syncthreads();
    if (tid < DMID) {
        float v = b1[tid];
#pragma unroll 4
        for (int k = 0; k < HIDX; k++) v += zp[k] * w1[k * DMID + tid];
        a[tid] = mishf(v);
    }
    __syncthreads();
    if (tid < DIMX) {
        float v = b2[tid];
#pragma unroll 4
        for (int k = 0; k < DMID; k++) v += a[k] * w2[k * DIMX + tid];
        xr[row * DIMX + tid] = v;
    }
}

extern "C" void kernel_launch(void* const* d_in, const int* in_sizes, int n_in,
                              void* d_out, int out_size, void* d_ws, size_t ws_size,
                              hipStream_t stream) {
    const float* x      = (const float*)d_in[0];
    const int*   batch  = (const int*)d_in[1];
    const float* rank_w = (const float*)d_in[2];
    const float* rank_b = (const float*)d_in[3];
    const float* vw1    = (const float*)d_in[4];
    const float* vb1    = (const float*)d_in[5];
    const float* vlg    = (const float*)d_in[6];
    const float* vlb    = (const float*)d_in[7];
    const float* vw2    = (const float*)d_in[8];
    const float* vb2    = (const float*)d_in[9];
    const float* cw     = (const float*)d_in[10];
    const float* cb     = (const float*)d_in[11];
    const float* sw1    = (const float*)d_in[12];
    const float* sb1    = (const float*)d_in[13];
    const float* slg    = (const float*)d_in[14];
    const float* slb    = (const float*)d_in[15];
    const float* sw2    = (const float*)d_in[16];
    const float* sb2    = (const float*)d_in[17];
    const float* dw1    = (const float*)d_in[18];
    const float* db1    = (const float*)d_in[19];
    const float* dw2    = (const float*)d_in[20];
    const float* db2    = (const float*)d_in[21];

    char* ws = (char*)d_ws;
    size_t off = 0;
    auto alloc = [&](size_t bytes) {
        void* p = ws + off;
        off += (bytes + 255) & ~(size_t)255;
        return p;
    };
    float* mag  = (float*)alloc((size_t)NTOTX * 4);
    float* zim  = (float*)alloc((size_t)NBX * HIDX * 4);
    float* zcre = (float*)alloc((size_t)NBX * HIDX * 4);
    int*   npi  = (int*)alloc((size_t)NBX * 4);
    float* wI1  = (float*)alloc((size_t)DIMX * VMID * 4);
    float* wI2  = (float*)alloc((size_t)VMID * HIDX * 4);
    float* h    = (float*)alloc((size_t)NTOTX * HIDX * 4);

    float* out_xr   = (float*)d_out;
    float* out_mask = out_xr + (size_t)NBX * NMAXX * DIMX;
    float* out_np   = out_mask + (size_t)NBX * NMAXX;

    hipLaunchKernelGGL(k_wt,   dim3((DIMX * VMID + VMID * HIDX + 255) / 256), dim3(256), 0, stream,
                       vw1, vw2, wI1, wI2);
    hipLaunchKernelGGL(k_enc,  dim3(NTOTX / EROWS), dim3(256), 0, stream,
                       x, rank_w, rank_b, (const float4*)wI1, vb1, vlg, vlb,
                       (const float4*)wI2, vb2, h, mag);
    hipLaunchKernelGGL(k_z,    dim3(NBX), dim3(HIDX), 0, stream,
                       h, batch, mag, cw, cb,
                       sw1, sb1, slg, slb, sw2, sb2,
                       zcre, zim, out_mask, out_np, npi);
    hipLaunchKernelGGL(k_dec,  dim3(NMAXX, NBX), dim3(256), 0, stream,
                       zcre, zim, npi, dw1, db1, dw2, db2, out_xr);
    (void)in_sizes; (void)n_in; (void)out_size; (void)ws_size;
}

// Round 13
// 160.242 us; speedup vs baseline: 1.0075x; 1.0075x over previous
//
#include <hip/hip_runtime.h>
#include <math.h>

#define DIMX 128
#define HIDX 256
#define NBX 2048
#define NTOTX 32768
#define NMAXX 32
#define VMID 192
#define SMID 128
#define DMID 192

#define EROWS 64
#define SP 66         // [k][r] pitch (floats): float2-aligned; GEMM reads are broadcast
#define NSEGMAX 128   // segment-size cap (multinomial mean 16, P(n>60) ~ 1e-16)

__device__ __forceinline__ float mishf(float v) {
    // exact identity: tanh(log1p(e^v)) = (u^2+2u)/(u^2+2u+2), u=e^v
    if (v > 20.0f) return v;          // tanh(softplus(v)) == 1.0f in fp32
    float u = expf(v);
    float t = u * (u + 2.0f);
    return v * (t / (t + 2.0f));
}

// one-time weight repack: wI[kg][col][kk] = w[(4kg+kk)][col]; also resets wcount
__global__ void k_wt(const float* __restrict__ w1, const float* __restrict__ w2,
                     float* __restrict__ wI1, float* __restrict__ wI2,
                     int* __restrict__ wcount) {
    int i = blockIdx.x * blockDim.x + threadIdx.x;
    if (i == 0) wcount[0] = 0;
    if (i < DIMX * VMID) {
        int k = i / VMID, c = i % VMID;
        wI1[((k >> 2) * VMID + c) * 4 + (k & 3)] = w1[i];
    }
    int i2 = i - DIMX * VMID;
    if (i2 >= 0 && i2 < VMID * HIDX) {
        int k = i2 / HIDX, c = i2 % HIDX;
        wI2[((k >> 2) * HIDX + c) * 4 + (k & 3)] = w2[i2];
    }
}

// fused encoder + mag: lane=column, 8 rows/thread, 64 rows/block (8 waves).
// Weights: coalesced float4 (4 k-steps per load) from repacked wI1/wI2;
// x^T broadcast from LDS (wave-uniform addresses).  [R10 best: ~85 us]
__global__ __launch_bounds__(512, 4) void k_enc(const float* __restrict__ x,
    const float* __restrict__ rw, const float* __restrict__ rb,
    const float4* __restrict__ wI1, const float* __restrict__ b1,
    const float* __restrict__ g1, const float* __restrict__ be1,
    const float4* __restrict__ wI2, const float* __restrict__ b2,
    float* __restrict__ h, float* __restrict__ mag) {
    __shared__ __align__(16) float sT[VMID * SP];  // xT[128][66] then actT[192][66]
    int tid = threadIdx.x;
    int rowbase = blockIdx.x * EROWS;

    // stage x^T: coalesced float4 reads
#pragma unroll
    for (int it = 0; it < 4; it++) {
        int idx = it * 512 + tid;
        int r = idx >> 5, kq = idx & 31;
        float4 v = ((const float4*)x)[(size_t)(rowbase + r) * 32 + kq];
        sT[(4 * kq + 0) * SP + r] = v.x;
        sT[(4 * kq + 1) * SP + r] = v.y;
        sT[(4 * kq + 2) * SP + r] = v.z;
        sT[(4 * kq + 3) * SP + r] = v.w;
    }
    __syncthreads();

    // mag = x . rank_w (wave 0; xT read-only here)
    if (tid < EROWS) {
        float s = 0.0f;
        for (int k = 0; k < DIMX; k++) s += sT[k * SP + tid] * rw[k];
        mag[rowbase + tid] = s + rb[0];
    }

    int c = tid & 63;      // col base (lane)
    int rg = tid >> 6;     // row group of 8 (wave-uniform)
    int r0 = rg * 8;

    // ---- GEMM1: per 4-k group: 3 coalesced f4 weight loads, 96 FMA ----
    float a0[8], a1[8], a2[8];
#pragma unroll
    for (int i = 0; i < 8; i++) { a0[i] = 0.f; a1[i] = 0.f; a2[i] = 0.f; }
    const float4* w1g = wI1 + c;
#pragma unroll 4
    for (int kg = 0; kg < DIMX / 4; kg++) {
        float4 wa = w1g[kg * VMID];
        float4 wb = w1g[kg * VMID + 64];
        float4 wc = w1g[kg * VMID + 128];
        const float waA[4] = {wa.x, wa.y, wa.z, wa.w};
        const float wbA[4] = {wb.x, wb.y, wb.z, wb.w};
        const float wcA[4] = {wc.x, wc.y, wc.z, wc.w};
#pragma unroll
        for (int kk = 0; kk < 4; kk++) {
            const float2* xp = (const float2*)&sT[(4 * kg + kk) * SP + r0];
            float2 t0 = xp[0], t1 = xp[1], t2 = xp[2], t3 = xp[3];
            float xv[8] = {t0.x, t0.y, t1.x, t1.y, t2.x, t2.y, t3.x, t3.y};
#pragma unroll
            for (int i = 0; i < 8; i++) {
                a0[i] += waA[kk] * xv[i];
                a1[i] += wbA[kk] * xv[i];
                a2[i] += wcA[kk] * xv[i];
            }
        }
    }

    // ---- LayerNorm + mish (registers + shuffles only) ----
    float b1a = b1[c], b1b = b1[c + 64], b1c = b1[c + 128];
    float g1a = g1[c], g1b = g1[c + 64], g1c = g1[c + 128];
    float e1a = be1[c], e1b = be1[c + 64], e1c = be1[c + 128];
#pragma unroll
    for (int i = 0; i < 8; i++) {
        float v0 = a0[i] + b1a, v1 = a1[i] + b1b, v2 = a2[i] + b1c;
        float s = v0 + v1 + v2;
#pragma unroll
        for (int off = 32; off; off >>= 1) s += __shfl_xor(s, off, 64);
        float mean = s / 192.0f;
        float d0 = v0 - mean, d1 = v1 - mean, d2 = v2 - mean;
        float q = d0 * d0 + d1 * d1 + d2 * d2;
#pragma unroll
        for (int off = 32; off; off >>= 1) q += __shfl_xor(q, off, 64);
        float inv = 1.0f / sqrtf(q / 192.0f + 1e-5f);
        a0[i] = mishf(d0 * inv * g1a + e1a);
        a1[i] = mishf(d1 * inv * g1b + e1b);
        a2[i] = mishf(d2 * inv * g1c + e1c);
    }
    __syncthreads();   // all GEMM1 LDS reads done before overwrite
#pragma unroll
    for (int i = 0; i < 8; i++) {
        sT[c * SP + r0 + i]          = a0[i];
        sT[(c + 64) * SP + r0 + i]   = a1[i];
        sT[(c + 128) * SP + r0 + i]  = a2[i];
    }
    __syncthreads();

    // ---- GEMM2: per 4-k group: 4 coalesced f4 weight loads, 128 FMA ----
    float c0[8], c1[8], c2[8], c3[8];
#pragma unroll
    for (int i = 0; i < 8; i++) { c0[i] = 0.f; c1[i] = 0.f; c2[i] = 0.f; c3[i] = 0.f; }
    const float4* w2g = wI2 + c;
#pragma unroll 4
    for (int kg = 0; kg < VMID / 4; kg++) {
        float4 wa = w2g[kg * HIDX];
        float4 wb = w2g[kg * HIDX + 64];
        float4 wc = w2g[kg * HIDX + 128];
        float4 wd = w2g[kg * HIDX + 192];
        const float waA[4] = {wa.x, wa.y, wa.z, wa.w};
        const float wbA[4] = {wb.x, wb.y, wb.z, wb.w};
        const float wcA[4] = {wc.x, wc.y, wc.z, wc.w};
        const float wdA[4] = {wd.x, wd.y, wd.z, wd.w};
#pragma unroll
        for (int kk = 0; kk < 4; kk++) {
            const float2* ap = (const float2*)&sT[(4 * kg + kk) * SP + r0];
            float2 t0 = ap[0], t1 = ap[1], t2 = ap[2], t3 = ap[3];
            float av[8] = {t0.x, t0.y, t1.x, t1.y, t2.x, t2.y, t3.x, t3.y};
#pragma unroll
            for (int i = 0; i < 8; i++) {
                c0[i] += waA[kk] * av[i];
                c1[i] += wbA[kk] * av[i];
                c2[i] += wcA[kk] * av[i];
                c3[i] += wdA[kk] * av[i];
            }
        }
    }
    float b2a = b2[c], b2b = b2[c + 64], b2c = b2[c + 128], b2d = b2[c + 192];
#pragma unroll
    for (int i = 0; i < 8; i++) {
        size_t row = (size_t)(rowbase + r0 + i);
        h[row * HIDX + c]        = c0[i] + b2a;
        h[row * HIDX + c + 64]   = c1[i] + b2b;
        h[row * HIDX + c + 128]  = c2[i] + b2c;
        h[row * HIDX + c + 192]  = c3[i] + b2d;
    }
}

// fused: seg-bounds + in-LDS rank + z (inline sincos) + size MLP + zc/mask/npred
// + zero-fill masked xr rows + append decode work-items to wlist
__global__ __launch_bounds__(256) void k_z(const float* __restrict__ h,
    const int* __restrict__ batch, const float* __restrict__ mag,
    const float* __restrict__ cw, const float* __restrict__ cb,
    const float* __restrict__ sw1, const float* __restrict__ sb1,
    const float* __restrict__ sg, const float* __restrict__ sbe,
    const float* __restrict__ sw2, const float* __restrict__ sb2,
    float* __restrict__ zcre, float* __restrict__ zim,
    float* __restrict__ out_mask, float* __restrict__ out_np,
    float* __restrict__ xr, int* __restrict__ wcount, int* __restrict__ wlist) {
    __shared__ float zrow[HIDX];
    __shared__ float magL[NSEGMAX];
    __shared__ int   ordL[NSEGMAX];
    __shared__ int   shs, shn;
    __shared__ float red0[2], red1[2], red2[2];
    __shared__ int   snpi;
    int b = blockIdx.x, j = threadIdx.x;
    if (j == 0) {
        int lo = 0, hi = NTOTX;
        while (lo < hi) { int m = (lo + hi) >> 1; if (batch[m] < b) lo = m + 1; else hi = m; }
        int stt = lo;
        hi = NTOTX;
        while (lo < hi) { int m = (lo + hi) >> 1; if (batch[m] <= b) lo = m + 1; else hi = m; }
        shs = stt; shn = lo - stt;
    }
    __syncthreads();
    int s = shs, n_true = shn;
    int n = (n_true < NSEGMAX) ? n_true : NSEGMAX;
    if (j < n) magL[j] = mag[s + j];
    __syncthreads();
    if (j < n) {                          // stable rank within segment (lexsort tie: idx)
        float mi = magL[j];
        int rk = 0;
        for (int q = 0; q < n; q++) {
            float mq = magL[q];
            rk += (mq < mi) || (mq == mi && q < j);
        }
        ordL[rk] = s + j;
    }
    __syncthreads();

    float t = (float)j * (1.0f / 255.0f);
    float zr = 0.f, zi = 0.f;
    int p = 0;
    for (; p + 1 < n; p += 2) {           // accumulation ORDER = p ascending (fp32-exact)
        int e0 = ordL[p], e1 = ordL[p + 1];
        float hv0 = h[(size_t)e0 * HIDX + j];
        float hv1 = h[(size_t)e1 * HIDX + j];
        float sv0, cv0, sv1, cv1;
        sincosf((t * (float)p) * 8.0f, &sv0, &cv0);
        sincosf((t * (float)(p + 1)) * 8.0f, &sv1, &cv1);
        zr += hv0 * cv0; zi += hv0 * sv0;
        zr += hv1 * cv1; zi += hv1 * sv1;
    }
    if (p < n) {
        int e = ordL[p];
        float hv = h[(size_t)e * HIDX + j];
        float sv, cv;
        sincosf((t * (float)p) * 8.0f, &sv, &cv);
        zr += hv * cv; zi += hv * sv;
    }
    float nf = (float)n_true;
    float zrev = zr + nf * cw[j] + cb[j];
    zrow[j] = zrev;
    zim[(size_t)b * HIDX + j] = zi;
    __syncthreads();

    // size MLP (threads 0..127 active; all threads hit barriers)
    float v = 0.0f;
    if (j < SMID) {
        v = sb1[j];
        for (int k = 0; k < HIDX; k++) v += zrow[k] * sw1[k * SMID + j];
    }
    float sa = v;
#pragma unroll
    for (int off = 32; off; off >>= 1) sa += __shfl_xor(sa, off, 64);
    if (j < SMID && (j & 63) == 0) red0[j >> 6] = sa;
    __syncthreads();
    float mean = (red0[0] + red0[1]) / 128.0f;
    float d = v - mean;
    float q2 = d * d;
#pragma unroll
    for (int off = 32; off; off >>= 1) q2 += __shfl_xor(q2, off, 64);
    if (j < SMID && (j & 63) == 0) red1[j >> 6] = q2;
    __syncthreads();
    float var = (red1[0] + red1[1]) / 128.0f;
    float p2 = 0.0f;
    if (j < SMID) {
        float lv = d * (1.0f / sqrtf(var + 1e-5f)) * sg[j] + sbe[j];
        p2 = mishf(lv) * sw2[j];
    }
#pragma unroll
    for (int off = 32; off; off >>= 1) p2 += __shfl_xor(p2, off, 64);
    if (j < SMID && (j & 63) == 0) red2[j >> 6] = p2;
    __syncthreads();
    float h2 = red2[0] + red2[1] + sb2[0];
    float npf = fmaxf(rintf(h2), 0.0f);     // rintf == round-half-even == jnp.round
    int npi = min((int)npf, NMAXX);
    zcre[(size_t)b * HIDX + j] = zrow[j] - (npf * cw[j] + cb[j]);
    if (j < NMAXX) out_mask[b * NMAXX + j] = (j < npi) ? 1.0f : 0.0f;
    if (j == 0) {
        out_np[b] = (float)npi;
        snpi = npi;
        int base = atomicAdd(wcount, npi);
        for (int m = 0; m < npi; m++) wlist[base + m] = (b << 5) | m;
    }
    __syncthreads();
    // zero-fill masked rows npi..31 of this batch's xr (disjoint from decoded rows)
    {
        int npi2 = snpi;
        float4* base4 = (float4*)(xr + (size_t)b * NMAXX * DIMX);
        for (int idx = npi2 * 32 + j; idx < NMAXX * 32; idx += 256)
            base4[idx] = make_float4(0.f, 0.f, 0.f, 0.f);
    }
}

// decoder over compacted worklist; grid-stride, one item per block-iteration
__global__ __launch_bounds__(256) void k_dec(const float* __restrict__ zcre,
    const float* __restrict__ zim, const int* __restrict__ wcount,
    const int* __restrict__ wlist,
    const float* __restrict__ w1, const float* __restrict__ b1,
    const float* __restrict__ w2, const float* __restrict__ b2,
    float* __restrict__ xr) {
    __shared__ float zp[HIDX];
    __shared__ float a[DMID];
    int tid = threadIdx.x;
    int count = *wcount;
    for (int it = blockIdx.x; it < count; it += gridDim.x) {
        int wv = wlist[it];
        int b = wv >> 5, m = wv & 31;
        {
            float t = (float)tid * (1.0f / 255.0f);
            float sv, cv;
            sincosf((t * (float)m) * 8.0f, &sv, &cv);
            zp[tid] = zcre[(size_t)b * HIDX + tid] * cv - zim[(size_t)b * HIDX + tid] * sv;
        }
        __syncthreads();
        if (tid < DMID) {
            float v = b1[tid];
#pragma unroll 4
            for (int k = 0; k < HIDX; k++) v += zp[k] * w1[k * DMID + tid];
            a[tid] = mishf(v);
        }
        __syncthreads();
        if (tid < DIMX) {
            float v = b2[tid];
#pragma unroll 4
            for (int k = 0; k < DMID; k++) v += a[k] * w2[k * DIMX + tid];
            xr[((size_t)b * NMAXX + m) * DIMX + tid] = v;
        }
        __syncthreads();
    }
}

extern "C" void kernel_launch(void* const* d_in, const int* in_sizes, int n_in,
                              void* d_out, int out_size, void* d_ws, size_t ws_size,
                              hipStream_t stream) {
    const float* x      = (const float*)d_in[0];
    const int*   batch  = (const int*)d_in[1];
    const float* rank_w = (const float*)d_in[2];
    const float* rank_b = (const float*)d_in[3];
    const float* vw1    = (const float*)d_in[4];
    const float* vb1    = (const float*)d_in[5];
    const float* vlg    = (const float*)d_in[6];
    const float* vlb    = (const float*)d_in[7];
    const float* vw2    = (const float*)d_in[8];
    const float* vb2    = (const float*)d_in[9];
    const float* cw     = (const float*)d_in[10];
    const float* cb     = (const float*)d_in[11];
    const float* sw1    = (const float*)d_in[12];
    const float* sb1    = (const float*)d_in[13];
    const float* slg    = (const float*)d_in[14];
    const float* slb    = (const float*)d_in[15];
    const float* sw2    = (const float*)d_in[16];
    const float* sb2    = (const float*)d_in[17];
    const float* dw1    = (const float*)d_in[18];
    const float* db1    = (const float*)d_in[19];
    const float* dw2    = (const float*)d_in[20];
    const float* db2    = (const float*)d_in[21];

    char* ws = (char*)d_ws;
    size_t off = 0;
    auto alloc = [&](size_t bytes) {
        void* p = ws + off;
        off += (bytes + 255) & ~(size_t)255;
        return p;
    };
    float* mag    = (float*)alloc((size_t)NTOTX * 4);
    float* zim    = (float*)alloc((size_t)NBX * HIDX * 4);
    float* zcre   = (float*)alloc((size_t)NBX * HIDX * 4);
    int*   wcount = (int*)alloc(256);
    int*   wlist  = (int*)alloc((size_t)NBX * NMAXX * 4);
    float* wI1    = (float*)alloc((size_t)DIMX * VMID * 4);
    float* wI2    = (float*)alloc((size_t)VMID * HIDX * 4);
    float* h      = (float*)alloc((size_t)NTOTX * HIDX * 4);

    float* out_xr   = (float*)d_out;
    float* out_mask = out_xr + (size_t)NBX * NMAXX * DIMX;
    float* out_np   = out_mask + (size_t)NBX * NMAXX;

    hipLaunchKernelGGL(k_wt,   dim3((DIMX * VMID + VMID * HIDX + 255) / 256), dim3(256), 0, stream,
                       vw1, vw2, wI1, wI2, wcount);
    hipLaunchKernelGGL(k_enc,  dim3(NTOTX / EROWS), dim3(512), 0, stream,
                       x, rank_w, rank_b, (const float4*)wI1, vb1, vlg, vlb,
                       (const float4*)wI2, vb2, h, mag);
    hipLaunchKernelGGL(k_z,    dim3(NBX), dim3(HIDX), 0, stream,
                       h, batch, mag, cw, cb,
                       sw1, sb1, slg, slb, sw2, sb2,
                       zcre, zim, out_mask, out_np, out_xr, wcount, wlist);
    hipLaunchKernelGGL(k_dec,  dim3(2048), dim3(256), 0, stream,
                       zcre, zim, wcount, wlist, dw1, db1, dw2, db2, out_xr);
    (void)in_sizes; (void)n_in; (void)out_size; (void)ws_size;
}

// Round 14
// 155.313 us; speedup vs baseline: 1.0395x; 1.0317x over previous
//
#include <hip/hip_runtime.h>
#include <math.h>

#define DIMX 128
#define HIDX 256
#define NBX 2048
#define NTOTX 32768
#define NMAXX 32
#define VMID 192
#define SMID 128
#define DMID 192

#define EROWS 64
#define SP 66         // [k][r] pitch (floats): float2-aligned; GEMM reads are broadcast
#define NSEGMAX 128   // segment-size cap (multinomial mean 16, P(n>60) ~ 1e-16)

typedef __attribute__((ext_vector_type(2))) float v2f;

__device__ __forceinline__ float mishf(float v) {
    // exact identity: tanh(log1p(e^v)) = (u^2+2u)/(u^2+2u+2), u=e^v
    if (v > 20.0f) return v;          // tanh(softplus(v)) == 1.0f in fp32
    float u = expf(v);
    float t = u * (u + 2.0f);
    return v * (t / (t + 2.0f));
}

// one-time weight repack: wI[kg][col][kk] = w[(4kg+kk)][col]; also resets wcount
__global__ void k_wt(const float* __restrict__ w1, const float* __restrict__ w2,
                     float* __restrict__ wI1, float* __restrict__ wI2,
                     int* __restrict__ wcount) {
    int i = blockIdx.x * blockDim.x + threadIdx.x;
    if (i == 0) wcount[0] = 0;
    if (i < DIMX * VMID) {
        int k = i / VMID, c = i % VMID;
        wI1[((k >> 2) * VMID + c) * 4 + (k & 3)] = w1[i];
    }
    int i2 = i - DIMX * VMID;
    if (i2 >= 0 && i2 < VMID * HIDX) {
        int k = i2 / HIDX, c = i2 % HIDX;
        wI2[((k >> 2) * HIDX + c) * 4 + (k & 3)] = w2[i2];
    }
}

// fused encoder + mag: lane=column, 8 rows/thread, 64 rows/block (8 waves).
// Weights: coalesced float4 (4 k per load, repacked). x via LDS broadcast.
// GEMM inner loops: packed v2f fma (row pairs) -> v_pk_fma_f32 on gfx950.
__global__ __launch_bounds__(512, 4) void k_enc(const float* __restrict__ x,
    const float* __restrict__ rw, const float* __restrict__ rb,
    const float4* __restrict__ wI1, const float* __restrict__ b1,
    const float* __restrict__ g1, const float* __restrict__ be1,
    const float4* __restrict__ wI2, const float* __restrict__ b2,
    float* __restrict__ h, float* __restrict__ mag) {
    __shared__ __align__(16) float sT[VMID * SP];  // xT[128][66] then actT[192][66]
    int tid = threadIdx.x;
    int rowbase = blockIdx.x * EROWS;

    // stage x^T: coalesced float4 reads
#pragma unroll
    for (int it = 0; it < 4; it++) {
        int idx = it * 512 + tid;
        int r = idx >> 5, kq = idx & 31;
        float4 v = ((const float4*)x)[(size_t)(rowbase + r) * 32 + kq];
        sT[(4 * kq + 0) * SP + r] = v.x;
        sT[(4 * kq + 1) * SP + r] = v.y;
        sT[(4 * kq + 2) * SP + r] = v.z;
        sT[(4 * kq + 3) * SP + r] = v.w;
    }
    __syncthreads();

    // mag = x . rank_w (wave 0; xT read-only here)
    if (tid < EROWS) {
        float s = 0.0f;
        for (int k = 0; k < DIMX; k++) s += sT[k * SP + tid] * rw[k];
        mag[rowbase + tid] = s + rb[0];
    }

    int c = tid & 63;      // col base (lane)
    int rg = tid >> 6;     // row group of 8 (wave-uniform)
    int r0 = rg * 8;

    // ---- GEMM1: 3 cols x 8 rows (4 row-pairs), packed fma ----
    v2f A0[4], A1[4], A2[4];
#pragma unroll
    for (int q = 0; q < 4; q++) { A0[q] = (v2f)0.0f; A1[q] = (v2f)0.0f; A2[q] = (v2f)0.0f; }
    const float4* w1g = wI1 + c;
#pragma unroll 4
    for (int kg = 0; kg < DIMX / 4; kg++) {
        float4 wa = w1g[kg * VMID];
        float4 wb = w1g[kg * VMID + 64];
        float4 wc = w1g[kg * VMID + 128];
        const float waA[4] = {wa.x, wa.y, wa.z, wa.w};
        const float wbA[4] = {wb.x, wb.y, wb.z, wb.w};
        const float wcA[4] = {wc.x, wc.y, wc.z, wc.w};
#pragma unroll
        for (int kk = 0; kk < 4; kk++) {
            const v2f* xp = (const v2f*)&sT[(4 * kg + kk) * SP + r0];
            v2f x0 = xp[0], x1 = xp[1], x2 = xp[2], x3 = xp[3];
            v2f wa2 = {waA[kk], waA[kk]};
            v2f wb2 = {wbA[kk], wbA[kk]};
            v2f wc2 = {wcA[kk], wcA[kk]};
            A0[0] = __builtin_elementwise_fma(wa2, x0, A0[0]);
            A0[1] = __builtin_elementwise_fma(wa2, x1, A0[1]);
            A0[2] = __builtin_elementwise_fma(wa2, x2, A0[2]);
            A0[3] = __builtin_elementwise_fma(wa2, x3, A0[3]);
            A1[0] = __builtin_elementwise_fma(wb2, x0, A1[0]);
            A1[1] = __builtin_elementwise_fma(wb2, x1, A1[1]);
            A1[2] = __builtin_elementwise_fma(wb2, x2, A1[2]);
            A1[3] = __builtin_elementwise_fma(wb2, x3, A1[3]);
            A2[0] = __builtin_elementwise_fma(wc2, x0, A2[0]);
            A2[1] = __builtin_elementwise_fma(wc2, x1, A2[1]);
            A2[2] = __builtin_elementwise_fma(wc2, x2, A2[2]);
            A2[3] = __builtin_elementwise_fma(wc2, x3, A2[3]);
        }
    }
    float a0[8], a1[8], a2[8];
#pragma unroll
    for (int q = 0; q < 4; q++) {
        a0[2 * q] = A0[q][0]; a0[2 * q + 1] = A0[q][1];
        a1[2 * q] = A1[q][0]; a1[2 * q + 1] = A1[q][1];
        a2[2 * q] = A2[q][0]; a2[2 * q + 1] = A2[q][1];
    }

    // ---- LayerNorm + mish (registers + shuffles only) ----
    float b1a = b1[c], b1b = b1[c + 64], b1c = b1[c + 128];
    float g1a = g1[c], g1b = g1[c + 64], g1c = g1[c + 128];
    float e1a = be1[c], e1b = be1[c + 64], e1c = be1[c + 128];
#pragma unroll
    for (int i = 0; i < 8; i++) {
        float v0 = a0[i] + b1a, v1 = a1[i] + b1b, v2 = a2[i] + b1c;
        float s = v0 + v1 + v2;
#pragma unroll
        for (int off = 32; off; off >>= 1) s += __shfl_xor(s, off, 64);
        float mean = s / 192.0f;
        float d0 = v0 - mean, d1 = v1 - mean, d2 = v2 - mean;
        float q = d0 * d0 + d1 * d1 + d2 * d2;
#pragma unroll
        for (int off = 32; off; off >>= 1) q += __shfl_xor(q, off, 64);
        float inv = 1.0f / sqrtf(q / 192.0f + 1e-5f);
        a0[i] = mishf(d0 * inv * g1a + e1a);
        a1[i] = mishf(d1 * inv * g1b + e1b);
        a2[i] = mishf(d2 * inv * g1c + e1c);
    }
    __syncthreads();   // all GEMM1 LDS reads done before overwrite
#pragma unroll
    for (int i = 0; i < 8; i++) {
        sT[c * SP + r0 + i]          = a0[i];
        sT[(c + 64) * SP + r0 + i]   = a1[i];
        sT[(c + 128) * SP + r0 + i]  = a2[i];
    }
    __syncthreads();

    // ---- GEMM2: 4 cols x 8 rows (4 row-pairs), packed fma ----
    v2f C0[4], C1[4], C2[4], C3[4];
#pragma unroll
    for (int q = 0; q < 4; q++) { C0[q] = (v2f)0.0f; C1[q] = (v2f)0.0f; C2[q] = (v2f)0.0f; C3[q] = (v2f)0.0f; }
    const float4* w2g = wI2 + c;
#pragma unroll 4
    for (int kg = 0; kg < VMID / 4; kg++) {
        float4 wa = w2g[kg * HIDX];
        float4 wb = w2g[kg * HIDX + 64];
        float4 wc = w2g[kg * HIDX + 128];
        float4 wd = w2g[kg * HIDX + 192];
        const float waA[4] = {wa.x, wa.y, wa.z, wa.w};
        const float wbA[4] = {wb.x, wb.y, wb.z, wb.w};
        const float wcA[4] = {wc.x, wc.y, wc.z, wc.w};
        const float wdA[4] = {wd.x, wd.y, wd.z, wd.w};
#pragma unroll
        for (int kk = 0; kk < 4; kk++) {
            const v2f* ap = (const v2f*)&sT[(4 * kg + kk) * SP + r0];
            v2f x0 = ap[0], x1 = ap[1], x2 = ap[2], x3 = ap[3];
            v2f wa2 = {waA[kk], waA[kk]};
            v2f wb2 = {wbA[kk], wbA[kk]};
            v2f wc2 = {wcA[kk], wcA[kk]};
            v2f wd2 = {wdA[kk], wdA[kk]};
            C0[0] = __builtin_elementwise_fma(wa2, x0, C0[0]);
            C0[1] = __builtin_elementwise_fma(wa2, x1, C0[1]);
            C0[2] = __builtin_elementwise_fma(wa2, x2, C0[2]);
            C0[3] = __builtin_elementwise_fma(wa2, x3, C0[3]);
            C1[0] = __builtin_elementwise_fma(wb2, x0, C1[0]);
            C1[1] = __builtin_elementwise_fma(wb2, x1, C1[1]);
            C1[2] = __builtin_elementwise_fma(wb2, x2, C1[2]);
            C1[3] = __builtin_elementwise_fma(wb2, x3, C1[3]);
            C2[0] = __builtin_elementwise_fma(wc2, x0, C2[0]);
            C2[1] = __builtin_elementwise_fma(wc2, x1, C2[1]);
            C2[2] = __builtin_elementwise_fma(wc2, x2, C2[2]);
            C2[3] = __builtin_elementwise_fma(wc2, x3, C2[3]);
            C3[0] = __builtin_elementwise_fma(wd2, x0, C3[0]);
            C3[1] = __builtin_elementwise_fma(wd2, x1, C3[1]);
            C3[2] = __builtin_elementwise_fma(wd2, x2, C3[2]);
            C3[3] = __builtin_elementwise_fma(wd2, x3, C3[3]);
        }
    }
    float b2a = b2[c], b2b = b2[c + 64], b2c = b2[c + 128], b2d = b2[c + 192];
#pragma unroll
    for (int q = 0; q < 4; q++) {
#pragma unroll
        for (int half = 0; half < 2; half++) {
            int i = 2 * q + half;
            size_t row = (size_t)(rowbase + r0 + i);
            h[row * HIDX + c]        = C0[q][half] + b2a;
            h[row * HIDX + c + 64]   = C1[q][half] + b2b;
            h[row * HIDX + c + 128]  = C2[q][half] + b2c;
            h[row * HIDX + c + 192]  = C3[q][half] + b2d;
        }
    }
}

// fused: seg-bounds + in-LDS rank + z (inline sincos) + size MLP + zc/mask/npred
// + zero-fill masked xr rows + append decode work-items to wlist
__global__ __launch_bounds__(256) void k_z(const float* __restrict__ h,
    const int* __restrict__ batch, const float* __restrict__ mag,
    const float* __restrict__ cw, const float* __restrict__ cb,
    const float* __restrict__ sw1, const float* __restrict__ sb1,
    const float* __restrict__ sg, const float* __restrict__ sbe,
    const float* __restrict__ sw2, const float* __restrict__ sb2,
    float* __restrict__ zcre, float* __restrict__ zim,
    float* __restrict__ out_mask, float* __restrict__ out_np,
    float* __restrict__ xr, int* __restrict__ wcount, int* __restrict__ wlist) {
    __shared__ float zrow[HIDX];
    __shared__ float magL[NSEGMAX];
    __shared__ int   ordL[NSEGMAX];
    __shared__ int   shs, shn;
    __shared__ float red0[2], red1[2], red2[2];
    __shared__ int   snpi;
    int b = blockIdx.x, j = threadIdx.x;
    if (j == 0) {
        int lo = 0, hi = NTOTX;
        while (lo < hi) { int m = (lo + hi) >> 1; if (batch[m] < b) lo = m + 1; else hi = m; }
        int stt = lo;
        hi = NTOTX;
        while (lo < hi) { int m = (lo + hi) >> 1; if (batch[m] <= b) lo = m + 1; else hi = m; }
        shs = stt; shn = lo - stt;
    }
    __syncthreads();
    int s = shs, n_true = shn;
    int n = (n_true < NSEGMAX) ? n_true : NSEGMAX;
    if (j < n) magL[j] = mag[s + j];
    __syncthreads();
    if (j < n) {                          // stable rank within segment (lexsort tie: idx)
        float mi = magL[j];
        int rk = 0;
        for (int q = 0; q < n; q++) {
            float mq = magL[q];
            rk += (mq < mi) || (mq == mi && q < j);
        }
        ordL[rk] = s + j;
    }
    __syncthreads();

    float t = (float)j * (1.0f / 255.0f);
    float zr = 0.f, zi = 0.f;
    int p = 0;
    for (; p + 1 < n; p += 2) {           // accumulation ORDER = p ascending (fp32-exact)
        int e0 = ordL[p], e1 = ordL[p + 1];
        float hv0 = h[(size_t)e0 * HIDX + j];
        float hv1 = h[(size_t)e1 * HIDX + j];
        float sv0, cv0, sv1, cv1;
        sincosf((t * (float)p) * 8.0f, &sv0, &cv0);
        sincosf((t * (float)(p + 1)) * 8.0f, &sv1, &cv1);
        zr += hv0 * cv0; zi += hv0 * sv0;
        zr += hv1 * cv1; zi += hv1 * sv1;
    }
    if (p < n) {
        int e = ordL[p];
        float hv = h[(size_t)e * HIDX + j];
        float sv, cv;
        sincosf((t * (float)p) * 8.0f, &sv, &cv);
        zr += hv * cv; zi += hv * sv;
    }
    float nf = (float)n_true;
    float zrev = zr + nf * cw[j] + cb[j];
    zrow[j] = zrev;
    zim[(size_t)b * HIDX + j] = zi;
    __syncthreads();

    // size MLP (threads 0..127 active; all threads hit barriers)
    float v = 0.0f;
    if (j < SMID) {
        v = sb1[j];
        for (int k = 0; k < HIDX; k++) v += zrow[k] * sw1[k * SMID + j];
    }
    float sa = v;
#pragma unroll
    for (int off = 32; off; off >>= 1) sa += __shfl_xor(sa, off, 64);
    if (j < SMID && (j & 63) == 0) red0[j >> 6] = sa;
    __syncthreads();
    float mean = (red0[0] + red0[1]) / 128.0f;
    float d = v - mean;
    float q2 = d * d;
#pragma unroll
    for (int off = 32; off; off >>= 1) q2 += __shfl_xor(q2, off, 64);
    if (j < SMID && (j & 63) == 0) red1[j >> 6] = q2;
    __syncthreads();
    float var = (red1[0] + red1[1]) / 128.0f;
    float p2 = 0.0f;
    if (j < SMID) {
        float lv = d * (1.0f / sqrtf(var + 1e-5f)) * sg[j] + sbe[j];
        p2 = mishf(lv) * sw2[j];
    }
#pragma unroll
    for (int off = 32; off; off >>= 1) p2 += __shfl_xor(p2, off, 64);
    if (j < SMID && (j & 63) == 0) red2[j >> 6] = p2;
    __syncthreads();
    float h2 = red2[0] + red2[1] + sb2[0];
    float npf = fmaxf(rintf(h2), 0.0f);     // rintf == round-half-even == jnp.round
    int npi = min((int)npf, NMAXX);
    zcre[(size_t)b * HIDX + j] = zrow[j] - (npf * cw[j] + cb[j]);
    if (j < NMAXX) out_mask[b * NMAXX + j] = (j < npi) ? 1.0f : 0.0f;
    if (j == 0) {
        out_np[b] = (float)npi;
        snpi = npi;
        int base = atomicAdd(wcount, npi);
        for (int m = 0; m < npi; m++) wlist[base + m] = (b << 5) | m;
    }
    __syncthreads();
    // zero-fill masked rows npi..31 of this batch's xr (disjoint from decoded rows)
    {
        int npi2 = snpi;
        float4* base4 = (float4*)(xr + (size_t)b * NMAXX * DIMX);
        for (int idx = npi2 * 32 + j; idx < NMAXX * 32; idx += 256)
            base4[idx] = make_float4(0.f, 0.f, 0.f, 0.f);
    }
}

// decoder over compacted worklist; grid-stride, one item per block-iteration
__global__ __launch_bounds__(256) void k_dec(const float* __restrict__ zcre,
    const float* __restrict__ zim, const int* __restrict__ wcount,
    const int* __restrict__ wlist,
    const float* __restrict__ w1, const float* __restrict__ b1,
    const float* __restrict__ w2, const float* __restrict__ b2,
    float* __restrict__ xr) {
    __shared__ float zp[HIDX];
    __shared__ float a[DMID];
    int tid = threadIdx.x;
    int count = *wcount;
    for (int it = blockIdx.x; it < count; it += gridDim.x) {
        int wv = wlist[it];
        int b = wv >> 5, m = wv & 31;
        {
            float t = (float)tid * (1.0f / 255.0f);
            float sv, cv;
            sincosf((t * (float)m) * 8.0f, &sv, &cv);
            zp[tid] = zcre[(size_t)b * HIDX + tid] * cv - zim[(size_t)b * HIDX + tid] * sv;
        }
        __syncthreads();
        if (tid < DMID) {
            float v = b1[tid];
#pragma unroll 4
            for (int k = 0; k < HIDX; k++) v += zp[k] * w1[k * DMID + tid];
            a[tid] = mishf(v);
        }
        __syncthreads();
        if (tid < DIMX) {
            float v = b2[tid];
#pragma unroll 4
            for (int k = 0; k < DMID; k++) v += a[k] * w2[k * DIMX + tid];
            xr[((size_t)b * NMAXX + m) * DIMX + tid] = v;
        }
        __syncthreads();
    }
}

extern "C" void kernel_launch(void* const* d_in, const int* in_sizes, int n_in,
                              void* d_out, int out_size, void* d_ws, size_t ws_size,
                              hipStream_t stream) {
    const float* x      = (const float*)d_in[0];
    const int*   batch  = (const int*)d_in[1];
    const float* rank_w = (const float*)d_in[2];
    const float* rank_b = (const float*)d_in[3];
    const float* vw1    = (const float*)d_in[4];
    const float* vb1    = (const float*)d_in[5];
    const float* vlg    = (const float*)d_in[6];
    const float* vlb    = (const float*)d_in[7];
    const float* vw2    = (const float*)d_in[8];
    const float* vb2    = (const float*)d_in[9];
    const float* cw     = (const float*)d_in[10];
    const float* cb     = (const float*)d_in[11];
    const float* sw1    = (const float*)d_in[12];
    const float* sb1    = (const float*)d_in[13];
    const float* slg    = (const float*)d_in[14];
    const float* slb    = (const float*)d_in[15];
    const float* sw2    = (const float*)d_in[16];
    const float* sb2    = (const float*)d_in[17];
    const float* dw1    = (const float*)d_in[18];
    const float* db1    = (const float*)d_in[19];
    const float* dw2    = (const float*)d_in[20];
    const float* db2    = (const float*)d_in[21];

    char* ws = (char*)d_ws;
    size_t off = 0;
    auto alloc = [&](size_t bytes) {
        void* p = ws + off;
        off += (bytes + 255) & ~(size_t)255;
        return p;
    };
    float* mag    = (float*)alloc((size_t)NTOTX * 4);
    float* zim    = (float*)alloc((size_t)NBX * HIDX * 4);
    float* zcre   = (float*)alloc((size_t)NBX * HIDX * 4);
    int*   wcount = (int*)alloc(256);
    int*   wlist  = (int*)alloc((size_t)NBX * NMAXX * 4);
    float* wI1    = (float*)alloc((size_t)DIMX * VMID * 4);
    float* wI2    = (float*)alloc((size_t)VMID * HIDX * 4);
    float* h      = (float*)alloc((size_t)NTOTX * HIDX * 4);

    float* out_xr   = (float*)d_out;
    float* out_mask = out_xr + (size_t)NBX * NMAXX * DIMX;
    float* out_np   = out_mask + (size_t)NBX * NMAXX;

    hipLaunchKernelGGL(k_wt,   dim3((DIMX * VMID + VMID * HIDX + 255) / 256), dim3(256), 0, stream,
                       vw1, vw2, wI1, wI2, wcount);
    hipLaunchKernelGGL(k_enc,  dim3(NTOTX / EROWS), dim3(512), 0, stream,
                       x, rank_w, rank_b, (const float4*)wI1, vb1, vlg, vlb,
                       (const float4*)wI2, vb2, h, mag);
    hipLaunchKernelGGL(k_z,    dim3(NBX), dim3(HIDX), 0, stream,
                       h, batch, mag, cw, cb,
                       sw1, sb1, slg, slb, sw2, sb2,
                       zcre, zim, out_mask, out_np, out_xr, wcount, wlist);
    hipLaunchKernelGGL(k_dec,  dim3(2048), dim3(256), 0, stream,
                       zcre, zim, wcount, wlist, dw1, db1, dw2, db2, out_xr);
    (void)in_sizes; (void)n_in; (void)out_size; (void)ws_size;
}